// Round 5
// baseline (605.142 us; speedup 1.0000x reference)
//
#include <hip/hip_runtime.h>
#include <hip/hip_bf16.h>
#include <stdint.h>

#define BB 8
#define TT 168
#define NN 1024
#define BN_ 8192
#define FD_ 16
#define EE 16384

typedef short short8 __attribute__((ext_vector_type(8)));
typedef __bf16 bf16x8 __attribute__((ext_vector_type(8)));
typedef float f32x4 __attribute__((ext_vector_type(4)));

#if __has_builtin(__builtin_amdgcn_exp2f)
#define EXP2(x) __builtin_amdgcn_exp2f(x)
#else
#define EXP2(x) exp2f(x)
#endif
#if __has_builtin(__builtin_amdgcn_rcpf)
#define RCPF(x) __builtin_amdgcn_rcpf(x)
#else
#define RCPF(x) (1.f / (x))
#endif
#define L2E 1.4426950408889634f
#define T2E 2.8853900817779268f

static __device__ __forceinline__ float b2f(ushort s) {
    unsigned u = ((unsigned)s) << 16;
    return __builtin_bit_cast(float, u);
}
static __device__ __forceinline__ ushort f2b(float f) {      // RNE
    unsigned u = __builtin_bit_cast(unsigned, f);
    unsigned lsb = (u >> 16) & 1u;
    u += 0x7fffu + lsb;
    return (ushort)(u >> 16);
}
static __device__ __forceinline__ ushort f2b_fast(float f) { // round-half-up, 2 ops
    unsigned u = __builtin_bit_cast(unsigned, f);
    return (ushort)((u + 0x8000u) >> 16);
}
static __device__ __forceinline__ f32x4 mfma16(short8 a, short8 b, f32x4 c) {
    return __builtin_amdgcn_mfma_f32_16x16x32_bf16(
        __builtin_bit_cast(bf16x8, a), __builtin_bit_cast(bf16x8, b), c, 0, 0, 0);
}

// ---------------------------------------------------------------------------
// Cast the MFMA-path f32 operands to bf16 in ws.
// ---------------------------------------------------------------------------
#define O_WIH 0
#define O_WHH 8192
#define O_STA 73728
#define O_FCS 335872
#define O_SW  401408
#define O_FW  405504
#define O_UW  406528
#define O_G0W 455680
#define O_G1W 521216
#define O_END 586752

__global__ void cast_kernel(const float* __restrict__ Wih, const float* __restrict__ Whh,
                            const float* __restrict__ sta, const float* __restrict__ fcst,
                            const float* __restrict__ sW, const float* __restrict__ fW,
                            const float* __restrict__ uW, const float* __restrict__ g0W,
                            const float* __restrict__ g1W, ushort* __restrict__ dst) {
    const int i = blockIdx.x * 256 + threadIdx.x;
    if (i >= O_END) return;
    float v;
    if      (i < O_WHH) v = Wih[i - O_WIH];
    else if (i < O_STA) v = Whh[i - O_WHH];
    else if (i < O_FCS) v = sta[i - O_STA];
    else if (i < O_SW)  v = fcst[i - O_FCS];
    else if (i < O_FW)  v = sW[i - O_SW];
    else if (i < O_UW)  v = fW[i - O_FW];
    else if (i < O_G0W) v = uW[i - O_UW];
    else if (i < O_G1W) v = g0W[i - O_G0W];
    else                v = g1W[i - O_G1W];
    dst[i] = f2b(v);
}

// ---------------------------------------------------------------------------
// LSTM: 16 nodes/block, 512 blocks, EIGHT waves (512 thr) -> 16 waves/CU.
// Wave w owns gate-cols {g*128 + w*16 + m}; 4 gate-groups per thread.
// Double-buffered LDS, one barrier/step, merged-rcp gates.
// ---------------------------------------------------------------------------
__global__ __launch_bounds__(512, 4) void lstm_kernel(
    const float* __restrict__ dyn,    // (B,T,N,16) f32
    const ushort* __restrict__ Wih,   // (512,16) bf16
    const ushort* __restrict__ Whh,   // (512,128) bf16
    const float* __restrict__ bih,
    const float* __restrict__ bhh,
    ushort* __restrict__ zsf)         // (8192,384) bf16, cols 0..127
{
    constexpr int HS = 168;           // [h(128) | x(16) | zero-pad(24)]
    __shared__ ushort hbuf[2][16 * HS];   // 10752 B

    const int tid = threadIdx.x;
    const int blk = blockIdx.x;
    const int b = blk >> 6;
    const int n0 = (blk & 63) << 4;
    const int w = tid >> 6, lane = tid & 63, quad = lane >> 4, m = lane & 15;
    const int u = w * 16 + m;         // unit column for this lane

    short8 Bf[5][4];
    float ci, cf, cg, co;
#pragma unroll
    for (int g = 0; g < 4; g++) {
        const int grow = g * 128 + u;
#pragma unroll
        for (int kt = 0; kt < 4; kt++)
            Bf[kt][g] = *(const short8*)(Whh + grow * 128 + kt * 32 + quad * 8);
        if (quad < 2) Bf[4][g] = *(const short8*)(Wih + grow * 16 + quad * 8);
        else          Bf[4][g] = short8{0, 0, 0, 0, 0, 0, 0, 0};
    }
    ci = -L2E * (bih[u] + bhh[u]);
    cf = -L2E * (bih[128 + u] + bhh[128 + u]);
    cg =  T2E * (bih[256 + u] + bhh[256 + u]);
    co = -L2E * (bih[384 + u] + bhh[384 + u]);

    float c[4];
#pragma unroll
    for (int r = 0; r < 4; r++) c[r] = 0.f;

    for (int i = tid; i < 2 * 16 * HS; i += 512) ((ushort*)hbuf)[i] = 0;
    __syncthreads();

    // x staging: threads 0..255 -> (node tid>>4, feat tid&15)
    const int xn = tid >> 4, xf = tid & 15;
    const size_t xbase = (size_t)b * TT * NN * FD_ + (size_t)(n0 + xn) * FD_ + xf;
    float xv = 0.f;
    if (tid < 256) {
        hbuf[0][xn * HS + 128 + xf] = f2b(dyn[xbase]);     // x(0)
        xv = dyn[xbase + (size_t)NN * FD_];                // x(1)
    }
    __syncthreads();

    for (int t = 0; t < TT; t++) {
        const ushort* rb = hbuf[t & 1];
        ushort* wb = hbuf[(t + 1) & 1];
        if (tid < 256) {
            if (t + 1 < TT) wb[xn * HS + 128 + xf] = f2b(xv);
            if (t + 2 < TT) xv = dyn[xbase + (size_t)(t + 2) * NN * FD_];
        }

        f32x4 acc[4];
#pragma unroll
        for (int g = 0; g < 4; g++) acc[g] = f32x4{0.f, 0.f, 0.f, 0.f};
#pragma unroll
        for (int kt = 0; kt < 5; kt++) {
            short8 a = *(const short8*)&rb[m * HS + kt * 32 + quad * 8];
#pragma unroll
            for (int g = 0; g < 4; g++)
                acc[g] = mfma16(a, Bf[kt][g], acc[g]);
        }

#pragma unroll
        for (int r = 0; r < 4; r++) {
            const int n = quad * 4 + r;
            const float Di = 1.f + EXP2(fmaf(acc[0][r], -L2E, ci));
            const float Df = 1.f + EXP2(fmaf(acc[1][r], -L2E, cf));
            const float Eg = EXP2(fmaf(acc[2][r], T2E, cg));
            const float Do = 1.f + EXP2(fmaf(acc[3][r], -L2E, co));
            const float R  = RCPF(Di * (1.f + Eg));
            const float sf = RCPF(Df);
            const float cc = fmaf(sf, c[r], (Eg - 1.f) * R);
            c[r] = cc;
            const float Ec = EXP2(T2E * cc);
            const float h = (Ec - 1.f) * RCPF(Do * (1.f + Ec));
            wb[n * HS + u] = f2b_fast(h);
            if (t == TT - 1) zsf[(size_t)(blk * 16 + n) * 384 + u] = f2b_fast(h);
        }
        __syncthreads();
    }
}

// ---------------------------------------------------------------------------
// Merged s/f GEMM + graph prep. Blocks 0..2047: GEMMs. Block 2048: prep
// (degree+wsum, 1024-scan via 256 threads, CSR fill, self-loop attr, se).
// ---------------------------------------------------------------------------
__global__ __launch_bounds__(256) void gemm_sf_prep_kernel(
    const ushort* __restrict__ staB, const ushort* __restrict__ sWB,
    const float* __restrict__ sb,
    const ushort* __restrict__ fcsB, const ushort* __restrict__ fWB,
    const float* __restrict__ fb, ushort* __restrict__ zsf,
    const int* __restrict__ ei, const float* __restrict__ ew,
    const float* __restrict__ We0, const float* __restrict__ ae0,
    const float* __restrict__ We1, const float* __restrict__ ae1,
    int* __restrict__ deg0, int* __restrict__ offs, float* __restrict__ loopea,
    int* __restrict__ eidx, float* __restrict__ se) {
    const int tid = threadIdx.x;
    if (blockIdx.x < 2048) {
        const int lane = tid & 63, quad = lane >> 4, m = lane & 15;
        int wave = blockIdx.x * 4 + (tid >> 6);
        const short8 z8 = short8{0, 0, 0, 0, 0, 0, 0, 0};
        short8 a, bf;
        int r0, c0, ocol;
        const float* bias;
        if (wave < 4096) {
            r0 = (wave >> 3) * 16; c0 = (wave & 7) * 16; ocol = 128; bias = sb;
            a  = *(const short8*)(staB + (size_t)(r0 + m) * 32 + quad * 8);
            bf = *(const short8*)(sWB + (size_t)(c0 + m) * 32 + quad * 8);
        } else {
            wave -= 4096;
            r0 = (wave >> 3) * 16; c0 = (wave & 7) * 16; ocol = 256; bias = fb;
            a  = (quad == 0) ? *(const short8*)(fcsB + (size_t)(r0 + m) * 8) : z8;
            bf = (quad == 0) ? *(const short8*)(fWB + (size_t)(c0 + m) * 8) : z8;
        }
        f32x4 acc = mfma16(a, bf, f32x4{0.f, 0.f, 0.f, 0.f});
        const float bv = bias[c0 + m];
#pragma unroll
        for (int r = 0; r < 4; r++) {
            const int row = r0 + quad * 4 + r;
            zsf[(size_t)row * 384 + ocol + c0 + m] = f2b(fmaxf(acc[r] + bv, 0.f));
        }
        return;
    }
    // ---- prep path (block 2048, 256 threads) ----
    __shared__ int degL[1024];
    __shared__ float wsL[1024];
    __shared__ int part[256];
    __shared__ float seL[8];
    for (int i = tid; i < 1024; i += 256) { degL[i] = 0; wsL[i] = 0.f; }
    if (tid < 8) seL[tid] = 0.f;
    __syncthreads();
    for (int e = tid; e < EE; e += 256) {
        const int d = ei[EE + e];
        atomicAdd(&degL[d], 1);
        atomicAdd(&wsL[d], ew[e]);
    }
    __syncthreads();
    const int d0 = degL[4 * tid], d1 = degL[4 * tid + 1];
    const int d2 = degL[4 * tid + 2], d3 = degL[4 * tid + 3];
    const int tot = d0 + d1 + d2 + d3;
    part[tid] = tot;
    __syncthreads();
    for (int o = 1; o < 256; o <<= 1) {
        const int v = (tid >= o) ? part[tid - o] : 0;
        __syncthreads();
        part[tid] += v;
        __syncthreads();
    }
    int base = part[tid] - tot;
    int ex[4];
    ex[0] = base; ex[1] = base + d0; ex[2] = ex[1] + d1; ex[3] = ex[2] + d2;
    const int dd4[4] = {d0, d1, d2, d3};
#pragma unroll
    for (int j = 0; j < 4; j++) {
        const int n = 4 * tid + j;
        offs[n] = ex[j];
        deg0[n] = dd4[j];
        loopea[n] = wsL[n] / fmaxf((float)dd4[j], 1.f);
    }
    __syncthreads();
#pragma unroll
    for (int j = 0; j < 4; j++) degL[4 * tid + j] = ex[j];   // cursor
    __syncthreads();
    for (int e = tid; e < EE; e += 256) {
        const int dd = ei[EE + e];
        const int slot = atomicAdd(&degL[dd], 1);
        eidx[slot] = e;
    }
    for (int i = tid; i < 1024; i += 256) {
        const int g = i >> 7, k = i & 127, head = g & 3;
        const float* W = (g >> 2) ? We1 : We0;
        const float* A = (g >> 2) ? ae1 : ae0;
        atomicAdd(&seL[g], W[head * 128 + k] * A[head * 128 + k]);
    }
    __syncthreads();
    if (tid < 8) se[tid] = seL[tid];
}

// ---------------------------------------------------------------------------
// Fusion GEMM: h = relu(zsf @ uW^T + ub), K=384; writes hB (bf16) + hF (f32).
// ---------------------------------------------------------------------------
__global__ __launch_bounds__(256) void gemm_fusion_kernel(
    const ushort* __restrict__ A, const ushort* __restrict__ Bt,
    const float* __restrict__ bias, ushort* __restrict__ hB, float* __restrict__ hF) {
    const int tid = threadIdx.x;
    const int lane = tid & 63, quad = lane >> 4, m = lane & 15;
    const int wave = blockIdx.x * 4 + (tid >> 6);
    const int r0 = (wave >> 3) * 16, c0 = (wave & 7) * 16;
    f32x4 acc = f32x4{0.f, 0.f, 0.f, 0.f};
#pragma unroll
    for (int kt = 0; kt < 12; kt++) {
        const int k = kt * 32 + quad * 8;
        short8 a  = *(const short8*)(A + (size_t)(r0 + m) * 384 + k);
        short8 bf = *(const short8*)(Bt + (size_t)(c0 + m) * 384 + k);
        acc = mfma16(a, bf, acc);
    }
    const int col = c0 + m;
    const float bv = bias[col];
#pragma unroll
    for (int r = 0; r < 4; r++) {
        const int row = r0 + quad * 4 + r;
        const float v = fmaxf(acc[r] + bv, 0.f);
        hB[(size_t)row * 128 + col] = f2b(v);
        hF[(size_t)row * 128 + col] = v;
    }
}

// ---------------------------------------------------------------------------
// Hop GEMM + fused attention scalars. Block = 16 rows; wave w = head w.
// ---------------------------------------------------------------------------
__global__ __launch_bounds__(256) void gemmatt_kernel(
    const ushort* __restrict__ hB, const ushort* __restrict__ W,
    const float* __restrict__ asrc, const float* __restrict__ adst,
    ushort* __restrict__ xl, float* __restrict__ as_, float* __restrict__ ad_) {
    const int tid = threadIdx.x;
    const int lane = tid & 63, quad = lane >> 4, m = lane & 15;
    const int w = tid >> 6;
    const int r0 = blockIdx.x * 16;
    f32x4 acc[8];
#pragma unroll
    for (int ct = 0; ct < 8; ct++) acc[ct] = f32x4{0.f, 0.f, 0.f, 0.f};
#pragma unroll
    for (int kt = 0; kt < 4; kt++) {
        const int k = kt * 32 + quad * 8;
        short8 a = *(const short8*)(hB + (size_t)(r0 + m) * 128 + k);
#pragma unroll
        for (int ct = 0; ct < 8; ct++) {
            short8 bf = *(const short8*)(W + (size_t)(w * 128 + ct * 16 + m) * 128 + k);
            acc[ct] = mfma16(a, bf, acc[ct]);
        }
    }
    float sa[4] = {0.f, 0.f, 0.f, 0.f}, sd[4] = {0.f, 0.f, 0.f, 0.f};
#pragma unroll
    for (int ct = 0; ct < 8; ct++) {
        const int col = w * 128 + ct * 16 + m;
        const float av = asrc[col], dv = adst[col];
#pragma unroll
        for (int r = 0; r < 4; r++) {
            const float v = acc[ct][r];
            xl[(size_t)(r0 + quad * 4 + r) * 512 + col] = f2b(v);
            sa[r] = fmaf(v, av, sa[r]);
            sd[r] = fmaf(v, dv, sd[r]);
        }
    }
#pragma unroll
    for (int o = 1; o < 16; o <<= 1) {
#pragma unroll
        for (int r = 0; r < 4; r++) {
            sa[r] += __shfl_xor(sa[r], o);
            sd[r] += __shfl_xor(sd[r], o);
        }
    }
    if (m == 0) {
#pragma unroll
        for (int r = 0; r < 4; r++) {
            const int node = r0 + quad * 4 + r;
            as_[node * 4 + w] = sa[r];
            ad_[node * 4 + w] = sd[r];
        }
    }
}

// ---------------------------------------------------------------------------
// Fused GAT hop, single pass, inline edge-exp: wave per (dst,batch);
// per-head numerator + denominator together; bias/relu/residual/LN.
// Hop1 (writeOut): emit final projection instead of writeback.
// ---------------------------------------------------------------------------
__global__ __launch_bounds__(256) void gat_kernel(
    float* __restrict__ hF, ushort* __restrict__ hB, const ushort* __restrict__ xl,
    const float* __restrict__ as_, const float* __restrict__ ad_,
    const int* __restrict__ eidx, const int* __restrict__ offs,
    const int* __restrict__ deg0, const float* __restrict__ loopea,
    const int* __restrict__ ei, const float* __restrict__ ew,
    const float* __restrict__ se4, const float* __restrict__ bias,
    const float* __restrict__ lng, const float* __restrict__ lnb, int relu,
    int writeOut, const float* __restrict__ oW, const float* __restrict__ ob,
    float* __restrict__ out) {
    const int lane = threadIdx.x & 63;
    const int v = blockIdx.x * 4 + (threadIdx.x >> 6);
    const int b = v >> 10, n = v & 1023;
    const int dg = deg0[n], off = offs[n];

    float se[4];
#pragma unroll
    for (int h = 0; h < 4; h++) se[h] = se4[h];

    // self loop
    const float lea = loopea[n];
    const float4 s4 = *(const float4*)(as_ + v * 4);
    const float4 d4 = *(const float4*)(ad_ + v * 4);
    const float* sp = (const float*)&s4;
    const float* dp = (const float*)&d4;
    float den[4], num0[4], num1[4];
#pragma unroll
    for (int h = 0; h < 4; h++) {
        float a = sp[h] + dp[h] + lea * se[h];
        a = (a < 0.f) ? 0.2f * a : a;
        const float p = EXP2(fminf(a, 60.f) * L2E);
        den[h] = p;
        num0[h] = p * b2f(xl[(size_t)v * 512 + h * 128 + lane]);
        num1[h] = p * b2f(xl[(size_t)v * 512 + h * 128 + 64 + lane]);
    }
    for (int i = 0; i < dg; i++) {
        const int e = eidx[off + i];
        const int src = b * 1024 + ei[e];
        const float eaw = ew[e];
        const float4 ss4 = *(const float4*)(as_ + src * 4);
        const float* ssp = (const float*)&ss4;
        const ushort* xr = xl + (size_t)src * 512;
#pragma unroll
        for (int h = 0; h < 4; h++) {
            float a = ssp[h] + dp[h] + eaw * se[h];
            a = (a < 0.f) ? 0.2f * a : a;
            const float p = EXP2(fminf(a, 60.f) * L2E);
            den[h] += p;
            num0[h] = fmaf(p, b2f(xr[h * 128 + lane]), num0[h]);
            num1[h] = fmaf(p, b2f(xr[h * 128 + 64 + lane]), num1[h]);
        }
    }
    float o0 = 0.f, o1 = 0.f;
#pragma unroll
    for (int h = 0; h < 4; h++) {
        const float inv = RCPF(den[h]);
        o0 = fmaf(num0[h], inv, o0);
        o1 = fmaf(num1[h], inv, o1);
    }

    float d0 = o0 * 0.25f + bias[lane];
    float d1 = o1 * 0.25f + bias[64 + lane];
    if (relu) { d0 = fmaxf(d0, 0.f); d1 = fmaxf(d1, 0.f); }
    const float x0 = hF[(size_t)v * 128 + lane] + d0;
    const float x1 = hF[(size_t)v * 128 + 64 + lane] + d1;

    float s = x0 + x1;
#pragma unroll
    for (int o = 32; o; o >>= 1) s += __shfl_xor(s, o);
    const float mu = s * (1.f / 128.f);
    const float e0 = x0 - mu, e1 = x1 - mu;
    float vs = e0 * e0 + e1 * e1;
#pragma unroll
    for (int o = 32; o; o >>= 1) vs += __shfl_xor(vs, o);
    const float r = rsqrtf(vs * (1.f / 128.f) + 1e-5f);
    const float y0 = e0 * r * lng[lane] + lnb[lane];
    const float y1 = e1 * r * lng[64 + lane] + lnb[64 + lane];
    if (writeOut) {
        float t = y0 * oW[lane] + y1 * oW[64 + lane];
#pragma unroll
        for (int o = 32; o; o >>= 1) t += __shfl_xor(t, o);
        if (lane == 0) out[v] = t + ob[0];
    } else {
        hF[(size_t)v * 128 + lane] = y0;
        hF[(size_t)v * 128 + 64 + lane] = y1;
        hB[(size_t)v * 128 + lane] = f2b(y0);
        hB[(size_t)v * 128 + 64 + lane] = f2b(y1);
    }
}

// ---------------------------------------------------------------------------
extern "C" void kernel_launch(void* const* d_in, const int* in_sizes, int n_in,
                              void* d_out, int out_size, void* d_ws, size_t ws_size,
                              hipStream_t stream) {
    const float* dyn  = (const float*)d_in[0];
    const float* fcst = (const float*)d_in[1];
    const float* sta  = (const float*)d_in[2];
    const int*   ei   = (const int*)d_in[3];
    const float* ew   = (const float*)d_in[4];
    const float* lWih = (const float*)d_in[5];
    const float* lWhh = (const float*)d_in[6];
    const float* lbih = (const float*)d_in[7];
    const float* lbhh = (const float*)d_in[8];
    const float* sW = (const float*)d_in[9];
    const float* sb = (const float*)d_in[10];
    const float* fW = (const float*)d_in[11];
    const float* fb = (const float*)d_in[12];
    const float* uW = (const float*)d_in[13];
    const float* ub = (const float*)d_in[14];
    const float* g0W  = (const float*)d_in[15];
    const float* g0as = (const float*)d_in[16];
    const float* g0ad = (const float*)d_in[17];
    const float* g0ae = (const float*)d_in[18];
    const float* g0We = (const float*)d_in[19];
    const float* g0b  = (const float*)d_in[20];
    const float* g1W  = (const float*)d_in[21];
    const float* g1as = (const float*)d_in[22];
    const float* g1ad = (const float*)d_in[23];
    const float* g1ae = (const float*)d_in[24];
    const float* g1We = (const float*)d_in[25];
    const float* g1b  = (const float*)d_in[26];
    const float* ln0g = (const float*)d_in[27];
    const float* ln0b = (const float*)d_in[28];
    const float* ln1g = (const float*)d_in[29];
    const float* ln1b = (const float*)d_in[30];
    const float* oW = (const float*)d_in[31];
    const float* ob = (const float*)d_in[32];

    char* p = (char*)d_ws;
    ushort* castB = (ushort*)p; p += (size_t)O_END * 2 + 512;
    ushort* zsf = (ushort*)p;  p += (size_t)BN_ * 384 * 2;
    float*  hF  = (float*)p;   p += (size_t)BN_ * 128 * 4;
    ushort* hB  = (ushort*)p;  p += (size_t)BN_ * 128 * 2;
    ushort* xl  = (ushort*)p;  p += (size_t)BN_ * 512 * 2;
    float*  asb = (float*)p;   p += (size_t)BN_ * 4 * 4;
    float*  adb = (float*)p;   p += (size_t)BN_ * 4 * 4;
    int*    deg0   = (int*)p;   p += 4096;
    int*    offs   = (int*)p;   p += 4096;
    float*  loopea = (float*)p; p += 4096;
    int*    eidx   = (int*)p;   p += (size_t)EE * 4;
    float*  se     = (float*)p; p += 256;

    const ushort* WihB = castB + O_WIH;
    const ushort* WhhB = castB + O_WHH;
    const ushort* staB = castB + O_STA;
    const ushort* fcsB = castB + O_FCS;
    const ushort* sWB  = castB + O_SW;
    const ushort* fWB  = castB + O_FW;
    const ushort* uWB  = castB + O_UW;
    const ushort* g0WB = castB + O_G0W;
    const ushort* g1WB = castB + O_G1W;

    cast_kernel<<<(O_END + 255) / 256, 256, 0, stream>>>(lWih, lWhh, sta, fcst, sW, fW,
                                                         uW, g0W, g1W, castB);
    lstm_kernel<<<512, 512, 0, stream>>>(dyn, WihB, WhhB, lbih, lbhh, zsf);
    gemm_sf_prep_kernel<<<2049, 256, 0, stream>>>(staB, sWB, sb, fcsB, fWB, fb, zsf,
                                                  ei, ew, g0We, g0ae, g1We, g1ae,
                                                  deg0, offs, loopea, eidx, se);
    gemm_fusion_kernel<<<1024, 256, 0, stream>>>(zsf, uWB, ub, hB, hF);

    // hop 0
    gemmatt_kernel<<<512, 256, 0, stream>>>(hB, g0WB, g0as, g0ad, xl, asb, adb);
    gat_kernel<<<2048, 256, 0, stream>>>(hF, hB, xl, asb, adb, eidx, offs, deg0,
                                         loopea, ei, ew, se, g0b, ln0g, ln0b, 1,
                                         0, oW, ob, (float*)d_out);
    // hop 1
    gemmatt_kernel<<<512, 256, 0, stream>>>(hB, g1WB, g1as, g1ad, xl, asb, adb);
    gat_kernel<<<2048, 256, 0, stream>>>(hF, hB, xl, asb, adb, eidx, offs, deg0,
                                         loopea, ei, ew, se + 4, g1b, ln1g, ln1b, 0,
                                         1, oW, ob, (float*)d_out);
}